// Round 13
// baseline (617.142 us; speedup 1.0000x reference)
//
#include <hip/hip_runtime.h>
#include <hip/hip_bf16.h>
#include <cstdint>

using bf16 = __hip_bfloat16;
typedef __attribute__((ext_vector_type(8))) __bf16 bf16x8;
typedef __attribute__((ext_vector_type(4))) float f32x4;
typedef __attribute__((ext_vector_type(4))) unsigned int u32x4;

#define SEQ    1024
#define BATCH  2
#define ROWS   (BATCH*SEQ)   // 2048
#define DMODEL 512
#define HIDDEN 2048
#define NHEADS 8
#define HD     64
#define VOCABN 50257
#define CHUNK  32
#define NCHUNK (SEQ/CHUNK)   // 32
#define QKVW   1536

__device__ __forceinline__ float gelu_tanh(float x) {
  float u = 0.7978845608028654f * (x + 0.044715f * x * x * x);
  return 0.5f * x * (1.0f + tanhf(u));
}

// ================= 8-phase 256x256 GEMM (head): R9-exact (best measured) ====
// BK=64, 128 KiB dynamic LDS, 8 waves, ko^(row&7) swizzle, tn-major bid.
// R12's XCD swizzle reverted: B (51.5MB) is L3-fit, and per m160 the chunked
// swizzle COSTS ~2% in the L3-fit regime (L3 is die-shared; swizzle only
// shuffles private-L2 ownership for no HBM saving).
__global__ __launch_bounds__(512, 2)
void head_gemm8(const bf16* __restrict__ A, const bf16* __restrict__ Bt,
                float* __restrict__ C, int N, int ntn)
{
  constexpr int NT = 8;             // K=512 / BK=64
  extern __shared__ char smem[];
  bf16* Al = (bf16*)smem;                    // [2][256][64]
  bf16* Bl = (bf16*)(smem + 65536);          // [2][256][64]
  const int t = threadIdx.x, lane = t & 63;
  const int w = t >> 6, wm = w >> 2, wn = w & 3;
  const int tm = blockIdx.x & 7, tn = blockIdx.x >> 3;   // tn-major (B-panel reuse)
  const int arow0 = tm * 256, brow0 = tn * 256;
  const int ko0 = lane >> 4;                 // logical 16B k-chunk 0..3
  const int kph1 = ((ko0 ^ (lane & 7)) << 4);  // physical byte offset (swizzled)
  const int kph2 = kph1 ^ 64;                  // logical ko0+4

  f32x4 acc[2][2][4][2];
#pragma unroll
  for (int i = 0; i < 2; ++i)
#pragma unroll
    for (int j = 0; j < 2; ++j)
#pragma unroll
      for (int m = 0; m < 4; ++m)
#pragma unroll
        for (int n = 0; n < 2; ++n) acc[i][j][m][n] = (f32x4){0.f, 0.f, 0.f, 0.f};

  auto stageA = [&](int s, int half, bf16* dstbuf) {
#pragma unroll
    for (int rep = 0; rep < 2; ++rep) {
      int slot = rep * 512 + t;
      int row = slot >> 3, ko = slot & 7;
      int kosrc = ko ^ (row & 7);            // pre-swizzled global source
      const bf16* src = A + (size_t)(arow0 + half * 128 + row) * 512 + s * 64 + kosrc * 8;
      bf16* dst = dstbuf + (half * 128 + row) * 64 + ko * 8;   // linear dest
      __builtin_amdgcn_global_load_lds(
          (const __attribute__((address_space(1))) unsigned int*)src,
          (__attribute__((address_space(3))) unsigned int*)dst, 16, 0, 0);
    }
  };
  auto stageB = [&](int s, int half, bf16* dstbuf) {
#pragma unroll
    for (int rep = 0; rep < 2; ++rep) {
      int slot = rep * 512 + t;
      int row = slot >> 3, ko = slot & 7;
      int kosrc = ko ^ (row & 7);
      int br = brow0 + half * 128 + row; br = br < N ? br : N - 1;
      const bf16* src = Bt + (size_t)br * 512 + s * 64 + kosrc * 8;
      bf16* dst = dstbuf + (half * 128 + row) * 64 + ko * 8;
      __builtin_amdgcn_global_load_lds(
          (const __attribute__((address_space(1))) unsigned int*)src,
          (__attribute__((address_space(3))) unsigned int*)dst, 16, 0, 0);
    }
  };

  bf16* Ac = Al;            // even tiles -> buf0
  bf16* Bc = Bl;
  bf16* An = Al + 16384;    // odd tiles -> buf1
  bf16* Bn = Bl + 16384;

  // prologue: tile0 all 4 halves + tile1 A-h0,B-h0; wait tile0; barrier
  stageA(0, 0, Ac); stageB(0, 0, Bc); stageA(0, 1, Ac); stageB(0, 1, Bc);
  stageA(1, 0, An); stageB(1, 0, Bn);
  asm volatile("s_waitcnt vmcnt(4)" ::: "memory");
  asm volatile("s_barrier" ::: "memory");

#define PH(MH, NH, AC, BC, STAGE_STMT, WAIT_STMT) do {                          \
    bf16x8 a_[4][2], b_[2][2];                                                  \
    _Pragma("unroll") for (int fm = 0; fm < 4; ++fm) {                          \
      const char* ap = (const char*)(AC) +                                      \
          ((MH) * 128 + wm * 64 + fm * 16 + (lane & 15)) * 128;                 \
      a_[fm][0] = __builtin_bit_cast(bf16x8, *(const u32x4*)(ap + kph1));       \
      a_[fm][1] = __builtin_bit_cast(bf16x8, *(const u32x4*)(ap + kph2));       \
    }                                                                           \
    _Pragma("unroll") for (int fn = 0; fn < 2; ++fn) {                          \
      const char* bp = (const char*)(BC) +                                      \
          ((NH) * 128 + wn * 32 + fn * 16 + (lane & 15)) * 128;                 \
      b_[fn][0] = __builtin_bit_cast(bf16x8, *(const u32x4*)(bp + kph1));       \
      b_[fn][1] = __builtin_bit_cast(bf16x8, *(const u32x4*)(bp + kph2));       \
    }                                                                           \
    STAGE_STMT;                                                                 \
    asm volatile("s_barrier" ::: "memory");                                     \
    asm volatile("s_waitcnt lgkmcnt(0)" ::: "memory");                          \
    __builtin_amdgcn_sched_barrier(0);                                          \
    __builtin_amdgcn_s_setprio(1);                                              \
    _Pragma("unroll") for (int fm = 0; fm < 4; ++fm)                            \
      _Pragma("unroll") for (int fn = 0; fn < 2; ++fn) {                        \
        acc[MH][NH][fm][fn] = __builtin_amdgcn_mfma_f32_16x16x32_bf16(          \
            a_[fm][0], b_[fn][0], acc[MH][NH][fm][fn], 0, 0, 0);                \
        acc[MH][NH][fm][fn] = __builtin_amdgcn_mfma_f32_16x16x32_bf16(          \
            a_[fm][1], b_[fn][1], acc[MH][NH][fm][fn], 0, 0, 0);                \
      }                                                                         \
    __builtin_amdgcn_s_setprio(0);                                              \
    WAIT_STMT;                                                                  \
    asm volatile("s_barrier" ::: "memory");                                     \
  } while (0)

#pragma unroll
  for (int I = 0; I < NT / 2; ++I) {
    const int u = 2 * I;
    // phases 0-3: compute tile u (buf0)
    PH(0, 0, Ac, Bc, { stageA(u + 1, 1, An); }, {});
    PH(0, 1, Ac, Bc, { stageB(u + 1, 1, Bn); }, {});
    PH(1, 0, Ac, Bc, { if (u + 2 < NT) stageA(u + 2, 0, Ac); }, {});
    PH(1, 1, Ac, Bc, { if (u + 2 < NT) stageB(u + 2, 0, Bc); },
       { if (u + 2 < NT) asm volatile("s_waitcnt vmcnt(4)" ::: "memory");
         else            asm volatile("s_waitcnt vmcnt(0)" ::: "memory"); });
    // phases 4-7: compute tile u+1 (buf1)
    PH(0, 0, An, Bn, { if (u + 2 < NT) stageA(u + 2, 1, Ac); }, {});
    PH(0, 1, An, Bn, { if (u + 2 < NT) stageB(u + 2, 1, Bc); }, {});
    PH(1, 0, An, Bn, { if (u + 3 < NT) stageA(u + 3, 0, An); }, {});
    PH(1, 1, An, Bn, { if (u + 3 < NT) stageB(u + 3, 0, Bn); },
       { if (u + 2 < NT) {
           if (u + 3 < NT) asm volatile("s_waitcnt vmcnt(4)" ::: "memory");
           else            asm volatile("s_waitcnt vmcnt(0)" ::: "memory");
         } });
  }
#undef PH

#pragma unroll
  for (int mh = 0; mh < 2; ++mh)
#pragma unroll
    for (int fm = 0; fm < 4; ++fm) {
      int row = arow0 + mh * 128 + wm * 64 + fm * 16 + (lane >> 4) * 4;
#pragma unroll
      for (int nh = 0; nh < 2; ++nh)
#pragma unroll
        for (int fn = 0; fn < 2; ++fn) {
          int col = brow0 + nh * 128 + wn * 32 + fn * 16 + (lane & 15);
          if (col < N) {
#pragma unroll
            for (int r = 0; r < 4; ++r)
              C[(size_t)(row + r) * N + col] = acc[mh][nh][fm][fn][r];
          }
        }
    }
}

// ========== mid GEMM: 128x64 tile, BK=64, 4 blocks/CU (R9-exact) ============
// EPI: 0 = f32 store; 1 = split-K partial (blockIdx.y = slice); 2 = bias+gelu bf16
template<int EPI>
__global__ __launch_bounds__(256, 4)
void gemm_mid(const bf16* __restrict__ A, const bf16* __restrict__ Bt,
              void* __restrict__ Cout, const float* __restrict__ bias,
              int M, int N, int K, int Ks, int ldc, int ntn)
{
  __shared__ __align__(16) bf16 As[128 * 64];   // 16 KB
  __shared__ __align__(16) bf16 Bs[64 * 64];    //  8 KB
  const int t = threadIdx.x;
  const int lane = t & 63;
  const int w = t >> 6;
  const int wr = w >> 1, wc = w & 1;           // wave grid 2m x 2n, wave: 64x32
  const int tm = blockIdx.x / ntn, tn = blockIdx.x % ntn;
  const int sk = blockIdx.y;
  const int kbeg = sk * Ks;
  const int rA = lane & 15;
  const int ko0 = lane >> 4;

  f32x4 acc[4][2];
#pragma unroll
  for (int m = 0; m < 4; ++m)
#pragma unroll
    for (int n = 0; n < 2; ++n) acc[m][n] = (f32x4){0.f, 0.f, 0.f, 0.f};

  for (int k0 = kbeg; k0 < kbeg + Ks; k0 += 64) {
#pragma unroll
    for (int rep = 0; rep < 4; ++rep) {        // A: 128 rows x 8 slots
      int c = rep * 256 + t;
      int row = c >> 3, ko = c & 7;
      const bf16* ga = A + (size_t)(tm * 128 + row) * K + k0 + (ko ^ (row & 7)) * 8;
      __builtin_amdgcn_global_load_lds(
          (const __attribute__((address_space(1))) unsigned int*)ga,
          (__attribute__((address_space(3))) unsigned int*)(As + row * 64 + ko * 8),
          16, 0, 0);
    }
#pragma unroll
    for (int rep = 0; rep < 2; ++rep) {        // B: 64 rows x 8 slots
      int c = rep * 256 + t;
      int row = c >> 3, ko = c & 7;
      const bf16* gb = Bt + (size_t)(tn * 64 + row) * K + k0 + (ko ^ (row & 7)) * 8;
      __builtin_amdgcn_global_load_lds(
          (const __attribute__((address_space(1))) unsigned int*)gb,
          (__attribute__((address_space(3))) unsigned int*)(Bs + row * 64 + ko * 8),
          16, 0, 0);
    }
    asm volatile("s_waitcnt vmcnt(0)" ::: "memory");
    __syncthreads();

    // k-half 0
    {
      bf16x8 af[4], bfv[2];
#pragma unroll
      for (int m = 0; m < 4; ++m) {
        int row = wr * 64 + m * 16 + rA;
        af[m] = __builtin_bit_cast(bf16x8,
            *(const u32x4*)((const char*)As + row * 128 + ((ko0 ^ (row & 7)) << 4)));
      }
#pragma unroll
      for (int n = 0; n < 2; ++n) {
        int row = wc * 32 + n * 16 + rA;
        bfv[n] = __builtin_bit_cast(bf16x8,
            *(const u32x4*)((const char*)Bs + row * 128 + ((ko0 ^ (row & 7)) << 4)));
      }
#pragma unroll
      for (int m = 0; m < 4; ++m)
#pragma unroll
        for (int n = 0; n < 2; ++n)
          acc[m][n] = __builtin_amdgcn_mfma_f32_16x16x32_bf16(af[m], bfv[n], acc[m][n], 0, 0, 0);
    }
    // k-half 1
    {
      bf16x8 af[4], bfv[2];
#pragma unroll
      for (int m = 0; m < 4; ++m) {
        int row = wr * 64 + m * 16 + rA;
        af[m] = __builtin_bit_cast(bf16x8,
            *(const u32x4*)((const char*)As + row * 128 + (((ko0 ^ (row & 7)) << 4) ^ 64)));
      }
#pragma unroll
      for (int n = 0; n < 2; ++n) {
        int row = wc * 32 + n * 16 + rA;
        bfv[n] = __builtin_bit_cast(bf16x8,
            *(const u32x4*)((const char*)Bs + row * 128 + (((ko0 ^ (row & 7)) << 4) ^ 64)));
      }
#pragma unroll
      for (int m = 0; m < 4; ++m)
#pragma unroll
        for (int n = 0; n < 2; ++n)
          acc[m][n] = __builtin_amdgcn_mfma_f32_16x16x32_bf16(af[m], bfv[n], acc[m][n], 0, 0, 0);
    }
    __syncthreads();
  }

#pragma unroll
  for (int m = 0; m < 4; ++m) {
    const int row = tm * 128 + wr * 64 + m * 16 + (lane >> 4) * 4;
#pragma unroll
    for (int n = 0; n < 2; ++n) {
      const int col = tn * 64 + wc * 32 + n * 16 + rA;
#pragma unroll
      for (int r = 0; r < 4; ++r) {
        float v = acc[m][n][r];
        if (EPI == 0) {
          ((float*)Cout)[(size_t)(row + r) * ldc + col] = v;
        } else if (EPI == 1) {
          ((float*)Cout)[(size_t)sk * M * N + (size_t)(row + r) * N + col] = v;
        } else {
          v += bias[col]; v = gelu_tanh(v);
          ((bf16*)Cout)[(size_t)(row + r) * ldc + col] = __float2bfloat16(v);
        }
      }
    }
  }
}

// ---------------- fallback GEMM (head only): 128^2, BK=32 -------------------
__global__ __launch_bounds__(256, 2)
void gemm_bt(const bf16* __restrict__ A, const bf16* __restrict__ Bt,
             void* __restrict__ Cout, const float* __restrict__ bias,
             int M, int N, int K, int ldc, int ntn)
{
  __shared__ __align__(16) bf16 As[128 * 32];
  __shared__ __align__(16) bf16 Bs[128 * 32];
  const int t = threadIdx.x;
  const int lane = t & 63;
  const int w = t >> 6;
  const int wr = w >> 1, wc = w & 1;
  const int tile = blockIdx.x;
  const int tm = tile / ntn, tn = tile % ntn;

  f32x4 acc[4][4];
#pragma unroll
  for (int m = 0; m < 4; ++m)
#pragma unroll
    for (int n = 0; n < 4; ++n) acc[m][n] = (f32x4){0.f, 0.f, 0.f, 0.f};

  const int rA = lane & 15;
  const int kq = (lane >> 4) * 8;
  const size_t a_row0 = (size_t)tm * 128;
  const int b_row0 = tn * 128;

  for (int k0 = 0; k0 < K; k0 += 32) {
#pragma unroll
    for (int i = 0; i < 2; ++i) {
      int chunk = i * 256 + t;
      int row = chunk >> 2;
      int kc = (chunk & 3) * 8;
      const bf16* ga = A + (a_row0 + row) * K + k0 + kc;
      int brow = b_row0 + row; brow = brow < N ? brow : N - 1;
      const bf16* gb = Bt + (size_t)brow * K + k0 + kc;
      __builtin_amdgcn_global_load_lds(
          (const __attribute__((address_space(1))) unsigned int*)ga,
          (__attribute__((address_space(3))) unsigned int*)(As + (size_t)(i * 256 + w * 64) * 8),
          16, 0, 0);
      __builtin_amdgcn_global_load_lds(
          (const __attribute__((address_space(1))) unsigned int*)gb,
          (__attribute__((address_space(3))) unsigned int*)(Bs + (size_t)(i * 256 + w * 64) * 8),
          16, 0, 0);
    }
    asm volatile("s_waitcnt vmcnt(0)" ::: "memory");
    __syncthreads();

    bf16x8 af[4], bfv[4];
#pragma unroll
    for (int m = 0; m < 4; ++m)
      af[m] = __builtin_bit_cast(bf16x8, *(const u32x4*)(As + (wr * 64 + m * 16 + rA) * 32 + kq));
#pragma unroll
    for (int n = 0; n < 4; ++n)
      bfv[n] = __builtin_bit_cast(bf16x8, *(const u32x4*)(Bs + (wc * 64 + n * 16 + rA) * 32 + kq));
#pragma unroll
    for (int m = 0; m < 4; ++m)
#pragma unroll
      for (int n = 0; n < 4; ++n)
        acc[m][n] = __builtin_amdgcn_mfma_f32_16x16x32_bf16(af[m], bfv[n], acc[m][n], 0, 0, 0);
    __syncthreads();
  }

#pragma unroll
  for (int m = 0; m < 4; ++m) {
    const int row = tm * 128 + wr * 64 + m * 16 + (lane >> 4) * 4;
#pragma unroll
    for (int n = 0; n < 4; ++n) {
      const int col = tn * 128 + wc * 64 + n * 16 + (lane & 15);
      if (col < N) {
#pragma unroll
        for (int r = 0; r < 4; ++r)
          ((float*)Cout)[(size_t)(row + r) * ldc + col] = acc[m][n][r];
      }
    }
  }
}

// ---------------- reduce split-K partials: + bias -> bf16 (mid MLP) ---------
__global__ __launch_bounds__(256)
void reduce_bias_bf16(const float* __restrict__ part, bf16* __restrict__ out,
                      const float* __restrict__ bias)
{
  int i = blockIdx.x * 256 + threadIdx.x;        // float4 index over ROWS*512/4
  const float4* p4 = (const float4*)part;
  const size_t str = (size_t)ROWS * DMODEL / 4;
  float4 v = p4[i];
  float4 v1 = p4[i + str], v2 = p4[i + 2 * str], v3 = p4[i + 3 * str];
  v.x += v1.x + v2.x + v3.x; v.y += v1.y + v2.y + v3.y;
  v.z += v1.z + v2.z + v3.z; v.w += v1.w + v2.w + v3.w;
  float4 bb = ((const float4*)bias)[i & (DMODEL / 4 - 1)];
  v.x += bb.x; v.y += bb.y; v.z += bb.z; v.w += bb.w;
  union { bf16 h[4]; uint2 u; } cv;
  cv.h[0] = __float2bfloat16(v.x); cv.h[1] = __float2bfloat16(v.y);
  cv.h[2] = __float2bfloat16(v.z); cv.h[3] = __float2bfloat16(v.w);
  ((uint2*)out)[i] = cv.u;
}

// -------- reduce split-K partials + residual-add into x + LayerNorm -> bf16 -
template<bool BIAS>
__global__ __launch_bounds__(256)
void reduce_resid_ln(const float* __restrict__ part, float* __restrict__ x,
                     const float* __restrict__ bias, const float* __restrict__ g,
                     const float* __restrict__ b, bf16* __restrict__ xn)
{
  int lane = threadIdx.x & 63;
  int row = blockIdx.x * 4 + (threadIdx.x >> 6);
  const float4* p4 = (const float4*)part;
  const size_t str = (size_t)ROWS * DMODEL / 4;
  size_t base = (size_t)row * (DMODEL / 4) + lane * 2;
  float4 a0 = p4[base], a1 = p4[base + 1];
#pragma unroll
  for (int s = 1; s < 4; ++s) {
    float4 q0 = p4[base + s * str], q1 = p4[base + 1 + s * str];
    a0.x += q0.x; a0.y += q0.y; a0.z += q0.z; a0.w += q0.w;
    a1.x += q1.x; a1.y += q1.y; a1.z += q1.z; a1.w += q1.w;
  }
  if (BIAS) {
    float4 b0 = ((const float4*)bias)[lane * 2];
    float4 b1 = ((const float4*)bias)[lane * 2 + 1];
    a0.x += b0.x; a0.y += b0.y; a0.z += b0.z; a0.w += b0.w;
    a1.x += b1.x; a1.y += b1.y; a1.z += b1.z; a1.w += b1.w;
  }
  float4* xr = (float4*)(x + (size_t)row * DMODEL);
  float4 x0 = xr[lane * 2], x1 = xr[lane * 2 + 1];
  x0.x += a0.x; x0.y += a0.y; x0.z += a0.z; x0.w += a0.w;
  x1.x += a1.x; x1.y += a1.y; x1.z += a1.z; x1.w += a1.w;
  xr[lane * 2] = x0; xr[lane * 2 + 1] = x1;
  float s  = x0.x + x0.y + x0.z + x0.w + x1.x + x1.y + x1.z + x1.w;
  float ss = x0.x*x0.x + x0.y*x0.y + x0.z*x0.z + x0.w*x0.w
           + x1.x*x1.x + x1.y*x1.y + x1.z*x1.z + x1.w*x1.w;
#pragma unroll
  for (int off = 32; off > 0; off >>= 1) { s += __shfl_xor(s, off); ss += __shfl_xor(ss, off); }
  float mu = s * (1.f / DMODEL);
  float inv = rsqrtf(ss * (1.f / DMODEL) - mu * mu + 1e-5f);
  int c0 = lane * 8;
  float vv[8] = {x0.x, x0.y, x0.z, x0.w, x1.x, x1.y, x1.z, x1.w};
#pragma unroll
  for (int j = 0; j < 8; ++j)
    xn[(size_t)row * DMODEL + c0 + j] = __float2bfloat16((vv[j] - mu) * inv * g[c0 + j] + b[c0 + j]);
}

// ---------------- Embedding + first LayerNorm -------------------------------
__global__ __launch_bounds__(256)
void embed_ln(const int* __restrict__ ids, const float* __restrict__ te,
              const float* __restrict__ pe, const float* __restrict__ g,
              const float* __restrict__ b, float* __restrict__ x, bf16* __restrict__ xn)
{
  int lane = threadIdx.x & 63;
  int row = blockIdx.x * 4 + (threadIdx.x >> 6);
  int sq = row & (SEQ - 1);
  int id = ids[row];
  const float4* tr = (const float4*)(te + (size_t)id * DMODEL);
  const float4* pr = (const float4*)(pe + (size_t)sq * DMODEL);
  float4 x0 = tr[lane * 2], x1 = tr[lane * 2 + 1];
  float4 p0 = pr[lane * 2], p1 = pr[lane * 2 + 1];
  x0.x += p0.x; x0.y += p0.y; x0.z += p0.z; x0.w += p0.w;
  x1.x += p1.x; x1.y += p1.y; x1.z += p1.z; x1.w += p1.w;
  float4* xr = (float4*)(x + (size_t)row * DMODEL);
  xr[lane * 2] = x0; xr[lane * 2 + 1] = x1;
  float s  = x0.x + x0.y + x0.z + x0.w + x1.x + x1.y + x1.z + x1.w;
  float ss = x0.x*x0.x + x0.y*x0.y + x0.z*x0.z + x0.w*x0.w
           + x1.x*x1.x + x1.y*x1.y + x1.z*x1.z + x1.w*x1.w;
#pragma unroll
  for (int off = 32; off > 0; off >>= 1) { s += __shfl_xor(s, off); ss += __shfl_xor(ss, off); }
  float mu = s * (1.f / DMODEL);
  float inv = rsqrtf(ss * (1.f / DMODEL) - mu * mu + 1e-5f);
  int c0 = lane * 8;
  float vv[8] = {x0.x, x0.y, x0.z, x0.w, x1.x, x1.y, x1.z, x1.w};
#pragma unroll
  for (int j = 0; j < 8; ++j)
    xn[(size_t)row * DMODEL + c0 + j] = __float2bfloat16((vv[j] - mu) * inv * g[c0 + j] + b[c0 + j]);
}

// ---------------- fp32 [R][C] -> bf16 [C][R] transpose+convert (batched) ----
__global__ __launch_bounds__(256)
void transpose_cvt(const float* __restrict__ in, bf16* __restrict__ out, int R, int C)
{
  __shared__ float tile[32][33];
  int mat = blockIdx.z;
  const float* src = in + (size_t)mat * R * C;
  bf16* dst = out + (size_t)mat * R * C;
  int c0 = blockIdx.x * 32, r0 = blockIdx.y * 32;
  int tx = threadIdx.x, ty = threadIdx.y;
#pragma unroll
  for (int i = ty; i < 32; i += 8)
    tile[i][tx] = src[(size_t)(r0 + i) * C + c0 + tx];
  __syncthreads();
#pragma unroll
  for (int i = ty; i < 32; i += 8)
    dst[(size_t)(c0 + i) * R + r0 + tx] = __float2bfloat16(tile[tx][i]);
}

// ---------------- Q/K/V weights -> fused transposed bf16 [l][1536][512] -----
__global__ __launch_bounds__(256)
void transpose_qkv(const float* __restrict__ Wq, const float* __restrict__ Wk,
                   const float* __restrict__ Wv, bf16* __restrict__ out)
{
  __shared__ float tile[32][33];
  int z = blockIdx.z;                 // l*3 + p
  int l = z / 3, p = z % 3;
  const float* src = (p == 0 ? Wq : (p == 1 ? Wk : Wv)) + (size_t)l * DMODEL * DMODEL;
  bf16* dst = out + (size_t)l * QKVW * DMODEL + (size_t)p * DMODEL * DMODEL;
  int c0 = blockIdx.x * 32, r0 = blockIdx.y * 32;
  int tx = threadIdx.x, ty = threadIdx.y;
#pragma unroll
  for (int i = ty; i < 32; i += 8)
    tile[i][tx] = src[(size_t)(r0 + i) * DMODEL + c0 + tx];
  __syncthreads();
#pragma unroll
  for (int i = ty; i < 32; i += 8)
    dst[(size_t)(c0 + i) * DMODEL + r0 + tx] = __float2bfloat16(tile[tx][i]);
}

// ---------------- fp32 -> bf16 convert (tok_emb for tied head) --------------
__global__ void cvt_bf16_k(const float* __restrict__ in, bf16* __restrict__ out, int n4)
{
  int i = blockIdx.x * 256 + threadIdx.x;
  if (i >= n4) return;
  float4 v = ((const float4*)in)[i];
  union { bf16 h[4]; uint2 u; } cv;
  cv.h[0] = __float2bfloat16(v.x); cv.h[1] = __float2bfloat16(v.y);
  cv.h[2] = __float2bfloat16(v.z); cv.h[3] = __float2bfloat16(v.w);
  ((uint2*)out)[i] = cv.u;
}

// ---------------- attention: per-chunk K^T V partial sums -------------------
__global__ __launch_bounds__(256)
void scan_ktv(const float* __restrict__ qkv, float* __restrict__ ktv)
{
  int blk = blockIdx.x;             // bh*NCHUNK + c
  int c = blk & (NCHUNK - 1), bh = blk >> 5;
  int b = bh >> 3, h = bh & 7;
  __shared__ float ks[CHUNK][64], vs[CHUNK][64];
  int t = threadIdx.x;
  size_t base = ((size_t)(b * SEQ + c * CHUNK)) * QKVW + h * HD;
#pragma unroll
  for (int i = 0; i < CHUNK * 64 / 256; ++i) {
    int idx = i * 256 + t;
    int s = idx >> 6, e = idx & 63;
    ks[s][e] = qkv[base + 512 + (size_t)s * QKVW + e];
    vs[s][e] = qkv[base + 1024 + (size_t)s * QKVW + e];
  }
  __syncthreads();
  int e = t >> 2, d0 = (t & 3) * 16;
  float acc[16];
#pragma unroll
  for (int j = 0; j < 16; ++j) acc[j] = 0.f;
  for (int s = 0; s < CHUNK; ++s) {
    float kv = ks[s][e];
#pragma unroll
    for (int j = 0; j < 16; ++j) acc[j] += kv * vs[s][d0 + j];
  }
  float* o = ktv + (size_t)blk * 4096 + e * 64 + d0;
#pragma unroll
  for (int j = 0; j < 16; ++j) o[j] = acc[j];
}

// ---- exclusive prefix-sum of ktv chunks (in-place), one block per bh -------
// Same summation order as the old in-scan loop (cp ascending) -> bitwise-
// identical results (R12: absmax unchanged); removes scan_attn's serial loop.
__global__ __launch_bounds__(256)
void prefix_ktv(float* __restrict__ ktv)
{
  int bh = blockIdx.x;              // 16
  int t = threadIdx.x;
  int e = t >> 2, d0 = (t & 3) * 16;
  float run[16];
#pragma unroll
  for (int j = 0; j < 16; ++j) run[j] = 0.f;
  for (int cp = 0; cp < NCHUNK; ++cp) {
    float* p = ktv + ((size_t)bh * NCHUNK + cp) * 4096 + e * 64 + d0;
    float tmp[16];
#pragma unroll
    for (int j = 0; j < 16; ++j) tmp[j] = p[j];
#pragma unroll
    for (int j = 0; j < 16; ++j) p[j] = run[j];
#pragma unroll
    for (int j = 0; j < 16; ++j) run[j] += tmp[j];
  }
}

// ---------------- attention: y = (QK^T . causal) V + Q M_prefix -------------
__global__ __launch_bounds__(256)
void scan_attn(const float* __restrict__ qkv, const float* __restrict__ ktv,
               bf16* __restrict__ y)
{
  int blk = blockIdx.x;
  int c = blk & (NCHUNK - 1), bh = blk >> 5;
  int b = bh >> 3, h = bh & 7;
  __shared__ float qs[CHUNK][65], ks[CHUNK][65], vs[CHUNK][65];
  __shared__ float Ss[CHUNK][CHUNK + 1];
  __shared__ float Ms[64][65];
  int t = threadIdx.x;
  size_t base = ((size_t)(b * SEQ + c * CHUNK)) * QKVW + h * HD;
#pragma unroll
  for (int i = 0; i < CHUNK * 64 / 256; ++i) {
    int idx = i * 256 + t;
    int s = idx >> 6, e = idx & 63;
    qs[s][e] = qkv[base + (size_t)s * QKVW + e];
    ks[s][e] = qkv[base + 512 + (size_t)s * QKVW + e];
    vs[s][e] = qkv[base + 1024 + (size_t)s * QKVW + e];
  }
  {  // load this chunk's exclusive-prefix M (precomputed by prefix_ktv)
    int e = t >> 2, d0 = (t & 3) * 16;
    const float* p = ktv + ((size_t)bh * NCHUNK + c) * 4096 + e * 64 + d0;
#pragma unroll
    for (int j = 0; j < 16; ++j) Ms[e][d0 + j] = p[j];
  }
  __syncthreads();
  {  // S = Q K^T with inclusive causal mask
    int si = t >> 3, j0 = (t & 7) * 4;
    float sa[4] = {0.f, 0.f, 0.f, 0.f};
    for (int e = 0; e < 64; ++e) {
      float qv = qs[si][e];
#pragma unroll
      for (int j = 0; j < 4; ++j) sa[j] += qv * ks[j0 + j][e];
    }
#pragma unroll
    for (int j = 0; j < 4; ++j) Ss[si][j0 + j] = (j0 + j <= si) ? sa[j] : 0.f;
  }
  __syncthreads();
  {  // y = S V + Q M
    int si = t >> 3, d0 = (t & 7) * 8;
    float ya[8];
#pragma unroll
    for (int j = 0; j < 8; ++j) ya[j] = 0.f;
    for (int sp = 0; sp < CHUNK; ++sp) {
      float sv = Ss[si][sp];
#pragma unroll
      for (int j = 0; j < 8; ++j) ya[j] += sv * vs[sp][d0 + j];
    }
    for (int e = 0; e < 64; ++e) {
      float qv = qs[si][e];
#pragma unroll
      for (int j = 0; j < 8; ++j) ya[j] += qv * Ms[e][d0 + j];
    }
    bf16* o = y + ((size_t)(b * SEQ + c * CHUNK + si)) * DMODEL + h * HD + d0;
#pragma unroll
    for (int j = 0; j < 8; ++j) o[j] = __float2bfloat16(ya[j]);
  }
}

// ---------------------------------------------------------------------------
extern "C" void kernel_launch(void* const* d_in, const int* in_sizes, int n_in,
                              void* d_out, int out_size, void* d_ws, size_t ws_size,
                              hipStream_t stream)
{
  const int*   ids  = (const int*)  d_in[0];
  const float* tok  = (const float*)d_in[1];
  const float* pos  = (const float*)d_in[2];
  const float* Wq   = (const float*)d_in[3];
  const float* Wk   = (const float*)d_in[4];
  const float* Wv   = (const float*)d_in[5];
  const float* Wo   = (const float*)d_in[6];
  const float* ln1g = (const float*)d_in[7];
  const float* ln1b = (const float*)d_in[8];
  const float* ln2g = (const float*)d_in[9];
  const float* ln2b = (const float*)d_in[10];
  const float* lnfg = (const float*)d_in[11];
  const float* lnfb = (const float*)d_in[12];
  const float* W1   = (const float*)d_in[13];
  const float* b1   = (const float*)d_in[14];
  const float* W2   = (const float*)d_in[15];
  const float* b2   = (const float*)d_in[16];
  float* out = (float*)d_out;

  char* ws = (char*)d_ws;
  size_t off = 0;
  auto alloc = [&](size_t bytes) { void* p = ws + off; off += (bytes + 255) & ~(size_t)255; return p; };
  bf16* QKVt = (bf16*)alloc((size_t)2 * QKVW * 512 * 2);
  bf16* Wot  = (bf16*)alloc((size_t)2 * 512 * 512 * 2);
  bf16* W1t  = (bf16*)alloc((size_t)6 * 512 * 2048 * 2);
  bf16* W2t  = (bf16*)alloc((size_t)6 * 2048 * 512 * 2);
  bf16* tokb = (bf16*)alloc((size_t)VOCABN * 512 * 2);
  float* x   = (float*)alloc((size_t)ROWS * 512 * 4);
  bf16*  xn  = (bf16*) alloc((size_t)ROWS * 512 * 2);
  bf16*  tbuf= (bf16*) alloc((size_t)ROWS * 512 * 2);
  bf16*  hbuf= (bf16*) alloc((size_t)ROWS * 2048 * 2);
  float* qkvf= (float*)alloc((size_t)ROWS * QKVW * 4);
  bf16*  yb  = (bf16*) alloc((size_t)ROWS * 512 * 2);
  float* ktv = (float*)alloc((size_t)16 * NCHUNK * 4096 * 4);
  float* part= (float*)alloc((size_t)4 * ROWS * 512 * 4);

  dim3 tb(32, 8);
  transpose_qkv<<<dim3(16, 16, 6), tb, 0, stream>>>(Wq, Wk, Wv, QKVt);
  transpose_cvt<<<dim3(16, 16, 2), tb, 0, stream>>>(Wo, Wot, 512, 512);
  transpose_cvt<<<dim3(64, 16, 6), tb, 0, stream>>>(W1, W1t, 512, 2048);
  transpose_cvt<<<dim3(16, 64, 6), tb, 0, stream>>>(W2, W2t, 2048, 512);
  int n4 = VOCABN * 512 / 4;
  cvt_bf16_k<<<(n4 + 255) / 256, 256, 0, stream>>>(tok, tokb, n4);

  embed_ln<<<ROWS / 4, 256, 0, stream>>>(ids, tok, pos, ln1g, ln1b, x, xn);

  for (int l = 0; l < 2; ++l) {
    // fused QKV projection: [2048,1536] fp32 — 384 blocks
    gemm_mid<0><<<dim3(16 * (QKVW / 64)), 256, 0, stream>>>(
        xn, QKVt + (size_t)l * QKVW * 512, qkvf, nullptr, ROWS, QKVW, 512, 512, QKVW, QKVW / 64);
    scan_ktv<<<16 * NCHUNK, 256, 0, stream>>>(qkvf, ktv);
    prefix_ktv<<<16, 256, 0, stream>>>(ktv);
    scan_attn<<<16 * NCHUNK, 256, 0, stream>>>(qkvf, ktv, yb);
    // Wo split-K=4 (512 blocks), reduce + residual + ln2
    gemm_mid<1><<<dim3(16 * 8, 4), 256, 0, stream>>>(
        yb, Wot + (size_t)l * 512 * 512, part, nullptr, ROWS, 512, 512, 128, 512, 8);
    reduce_resid_ln<false><<<ROWS / 4, 256, 0, stream>>>(
        part, x, nullptr, ln2g + l * 512, ln2b + l * 512, xn);

    const bf16* cur = xn;
    for (int m = 0; m < 3; ++m) {
      int lm = l * 3 + m;
      // W1: [2048,2048] gelu -> bf16 — 512 blocks
      gemm_mid<2><<<dim3(16 * (2048 / 64)), 256, 0, stream>>>(
          cur, W1t + (size_t)lm * 2048 * 512, hbuf, b1 + (size_t)lm * 2048,
          ROWS, 2048, 512, 512, 2048, 2048 / 64);
      // W2: split-K=4 (512 blocks)
      gemm_mid<1><<<dim3(16 * 8, 4), 256, 0, stream>>>(
          hbuf, W2t + (size_t)lm * 512 * 2048, part, nullptr, ROWS, 512, 2048, 512, 512, 8);
      if (m < 2) {
        reduce_bias_bf16<<<ROWS * 512 / 4 / 256, 256, 0, stream>>>(part, tbuf, b2 + (size_t)lm * 512);
        cur = tbuf;
      } else {
        const float* g = (l == 0) ? (ln1g + 512) : lnfg;
        const float* b = (l == 0) ? (ln1b + 512) : lnfb;
        reduce_resid_ln<true><<<ROWS / 4, 256, 0, stream>>>(part, x, b2 + (size_t)lm * 512, g, b, xn);
      }
    }
  }

  // tied head: R9-exact 8-phase 256^2, BK=64, 128 KiB dynamic LDS, tn-major
  int ntn_h = (VOCABN + 255) / 256;   // 197
  (void)hipFuncSetAttribute((const void*)head_gemm8,
                            hipFuncAttributeMaxDynamicSharedMemorySize, 131072);
  head_gemm8<<<dim3(8 * ntn_h), 512, 131072, stream>>>(xn, tokb, out, VOCABN, ntn_h);
  if (hipGetLastError() != hipSuccess) {
    // fallback: 128^2 m97-structure head
    gemm_bt<<<dim3((ROWS / 128) * ((VOCABN + 127) / 128)), 256, 0, stream>>>(
        xn, tokb, out, nullptr, ROWS, VOCABN, 512, VOCABN, (VOCABN + 127) / 128);
  }
}

// Round 14
// 585.586 us; speedup vs baseline: 1.0539x; 1.0539x over previous
//
#include <hip/hip_runtime.h>
#include <hip/hip_bf16.h>
#include <cstdint>

using bf16 = __hip_bfloat16;
typedef __attribute__((ext_vector_type(8))) __bf16 bf16x8;
typedef __attribute__((ext_vector_type(4))) float f32x4;
typedef __attribute__((ext_vector_type(4))) unsigned int u32x4;

#define SEQ    1024
#define BATCH  2
#define ROWS   (BATCH*SEQ)   // 2048
#define DMODEL 512
#define HIDDEN 2048
#define NHEADS 8
#define HD     64
#define VOCABN 50257
#define CHUNK  32
#define NCHUNK (SEQ/CHUNK)   // 32
#define QKVW   1536

__device__ __forceinline__ float gelu_tanh(float x) {
  float u = 0.7978845608028654f * (x + 0.044715f * x * x * x);
  return 0.5f * x * (1.0f + tanhf(u));
}

// ================= 8-phase 256x256 GEMM (head): R9-exact (best measured) ====
// BK=64, 128 KiB dynamic LDS, 8 waves, ko^(row&7) swizzle, tn-major bid.
__global__ __launch_bounds__(512, 2)
void head_gemm8(const bf16* __restrict__ A, const bf16* __restrict__ Bt,
                float* __restrict__ C, int N, int ntn)
{
  constexpr int NT = 8;             // K=512 / BK=64
  extern __shared__ char smem[];
  bf16* Al = (bf16*)smem;                    // [2][256][64]
  bf16* Bl = (bf16*)(smem + 65536);          // [2][256][64]
  const int t = threadIdx.x, lane = t & 63;
  const int w = t >> 6, wm = w >> 2, wn = w & 3;
  const int tm = blockIdx.x & 7, tn = blockIdx.x >> 3;   // tn-major (B-panel reuse)
  const int arow0 = tm * 256, brow0 = tn * 256;
  const int ko0 = lane >> 4;                 // logical 16B k-chunk 0..3
  const int kph1 = ((ko0 ^ (lane & 7)) << 4);  // physical byte offset (swizzled)
  const int kph2 = kph1 ^ 64;                  // logical ko0+4

  f32x4 acc[2][2][4][2];
#pragma unroll
  for (int i = 0; i < 2; ++i)
#pragma unroll
    for (int j = 0; j < 2; ++j)
#pragma unroll
      for (int m = 0; m < 4; ++m)
#pragma unroll
        for (int n = 0; n < 2; ++n) acc[i][j][m][n] = (f32x4){0.f, 0.f, 0.f, 0.f};

  auto stageA = [&](int s, int half, bf16* dstbuf) {
#pragma unroll
    for (int rep = 0; rep < 2; ++rep) {
      int slot = rep * 512 + t;
      int row = slot >> 3, ko = slot & 7;
      int kosrc = ko ^ (row & 7);            // pre-swizzled global source
      const bf16* src = A + (size_t)(arow0 + half * 128 + row) * 512 + s * 64 + kosrc * 8;
      bf16* dst = dstbuf + (half * 128 + row) * 64 + ko * 8;   // linear dest
      __builtin_amdgcn_global_load_lds(
          (const __attribute__((address_space(1))) unsigned int*)src,
          (__attribute__((address_space(3))) unsigned int*)dst, 16, 0, 0);
    }
  };
  auto stageB = [&](int s, int half, bf16* dstbuf) {
#pragma unroll
    for (int rep = 0; rep < 2; ++rep) {
      int slot = rep * 512 + t;
      int row = slot >> 3, ko = slot & 7;
      int kosrc = ko ^ (row & 7);
      int br = brow0 + half * 128 + row; br = br < N ? br : N - 1;
      const bf16* src = Bt + (size_t)br * 512 + s * 64 + kosrc * 8;
      bf16* dst = dstbuf + (half * 128 + row) * 64 + ko * 8;
      __builtin_amdgcn_global_load_lds(
          (const __attribute__((address_space(1))) unsigned int*)src,
          (__attribute__((address_space(3))) unsigned int*)dst, 16, 0, 0);
    }
  };

  bf16* Ac = Al;            // even tiles -> buf0
  bf16* Bc = Bl;
  bf16* An = Al + 16384;    // odd tiles -> buf1
  bf16* Bn = Bl + 16384;

  // prologue: tile0 all 4 halves + tile1 A-h0,B-h0; wait tile0; barrier
  stageA(0, 0, Ac); stageB(0, 0, Bc); stageA(0, 1, Ac); stageB(0, 1, Bc);
  stageA(1, 0, An); stageB(1, 0, Bn);
  asm volatile("s_waitcnt vmcnt(4)" ::: "memory");
  asm volatile("s_barrier" ::: "memory");

#define PH(MH, NH, AC, BC, STAGE_STMT, WAIT_STMT) do {                          \
    bf16x8 a_[4][2], b_[2][2];                                                  \
    _Pragma("unroll") for (int fm = 0; fm < 4; ++fm) {                          \
      const char* ap = (const char*)(AC) +                                      \
          ((MH) * 128 + wm * 64 + fm * 16 + (lane & 15)) * 128;                 \
      a_[fm][0] = __builtin_bit_cast(bf16x8, *(const u32x4*)(ap + kph1));       \
      a_[fm][1] = __builtin_bit_cast(bf16x8, *(const u32x4*)(ap + kph2));       \
    }                                                                           \
    _Pragma("unroll") for (int fn = 0; fn < 2; ++fn) {                          \
      const char* bp = (const char*)(BC) +                                      \
          ((NH) * 128 + wn * 32 + fn * 16 + (lane & 15)) * 128;                 \
      b_[fn][0] = __builtin_bit_cast(bf16x8, *(const u32x4*)(bp + kph1));       \
      b_[fn][1] = __builtin_bit_cast(bf16x8, *(const u32x4*)(bp + kph2));       \
    }                                                                           \
    STAGE_STMT;                                                                 \
    asm volatile("s_barrier" ::: "memory");                                     \
    asm volatile("s_waitcnt lgkmcnt(0)" ::: "memory");                          \
    __builtin_amdgcn_sched_barrier(0);                                          \
    __builtin_amdgcn_s_setprio(1);                                              \
    _Pragma("unroll") for (int fm = 0; fm < 4; ++fm)                            \
      _Pragma("unroll") for (int fn = 0; fn < 2; ++fn) {                        \
        acc[MH][NH][fm][fn] = __builtin_amdgcn_mfma_f32_16x16x32_bf16(          \
            a_[fm][0], b_[fn][0], acc[MH][NH][fm][fn], 0, 0, 0);                \
        acc[MH][NH][fm][fn] = __builtin_amdgcn_mfma_f32_16x16x32_bf16(          \
            a_[fm][1], b_[fn][1], acc[MH][NH][fm][fn], 0, 0, 0);                \
      }                                                                         \
    __builtin_amdgcn_s_setprio(0);                                              \
    WAIT_STMT;                                                                  \
    asm volatile("s_barrier" ::: "memory");                                     \
  } while (0)

#pragma unroll
  for (int I = 0; I < NT / 2; ++I) {
    const int u = 2 * I;
    // phases 0-3: compute tile u (buf0)
    PH(0, 0, Ac, Bc, { stageA(u + 1, 1, An); }, {});
    PH(0, 1, Ac, Bc, { stageB(u + 1, 1, Bn); }, {});
    PH(1, 0, Ac, Bc, { if (u + 2 < NT) stageA(u + 2, 0, Ac); }, {});
    PH(1, 1, Ac, Bc, { if (u + 2 < NT) stageB(u + 2, 0, Bc); },
       { if (u + 2 < NT) asm volatile("s_waitcnt vmcnt(4)" ::: "memory");
         else            asm volatile("s_waitcnt vmcnt(0)" ::: "memory"); });
    // phases 4-7: compute tile u+1 (buf1)
    PH(0, 0, An, Bn, { if (u + 2 < NT) stageA(u + 2, 1, Ac); }, {});
    PH(0, 1, An, Bn, { if (u + 2 < NT) stageB(u + 2, 1, Bc); }, {});
    PH(1, 0, An, Bn, { if (u + 3 < NT) stageA(u + 3, 0, An); }, {});
    PH(1, 1, An, Bn, { if (u + 3 < NT) stageB(u + 3, 0, Bn); },
       { if (u + 2 < NT) {
           if (u + 3 < NT) asm volatile("s_waitcnt vmcnt(4)" ::: "memory");
           else            asm volatile("s_waitcnt vmcnt(0)" ::: "memory");
         } });
  }
#undef PH

#pragma unroll
  for (int mh = 0; mh < 2; ++mh)
#pragma unroll
    for (int fm = 0; fm < 4; ++fm) {
      int row = arow0 + mh * 128 + wm * 64 + fm * 16 + (lane >> 4) * 4;
#pragma unroll
      for (int nh = 0; nh < 2; ++nh)
#pragma unroll
        for (int fn = 0; fn < 2; ++fn) {
          int col = brow0 + nh * 128 + wn * 32 + fn * 16 + (lane & 15);
          if (col < N) {
#pragma unroll
            for (int r = 0; r < 4; ++r)
              C[(size_t)(row + r) * N + col] = acc[mh][nh][fm][fn][r];
          }
        }
    }
}

// ========== mid GEMM: 128x64 tile, BK=64, 4 blocks/CU (R9-exact) ============
// EPI: 0 = f32 store; 1 = split-K partial (blockIdx.y = slice); 2 = bias+gelu bf16
template<int EPI>
__global__ __launch_bounds__(256, 4)
void gemm_mid(const bf16* __restrict__ A, const bf16* __restrict__ Bt,
              void* __restrict__ Cout, const float* __restrict__ bias,
              int M, int N, int K, int Ks, int ldc, int ntn)
{
  __shared__ __align__(16) bf16 As[128 * 64];   // 16 KB
  __shared__ __align__(16) bf16 Bs[64 * 64];    //  8 KB
  const int t = threadIdx.x;
  const int lane = t & 63;
  const int w = t >> 6;
  const int wr = w >> 1, wc = w & 1;           // wave grid 2m x 2n, wave: 64x32
  const int tm = blockIdx.x / ntn, tn = blockIdx.x % ntn;
  const int sk = blockIdx.y;
  const int kbeg = sk * Ks;
  const int rA = lane & 15;
  const int ko0 = lane >> 4;

  f32x4 acc[4][2];
#pragma unroll
  for (int m = 0; m < 4; ++m)
#pragma unroll
    for (int n = 0; n < 2; ++n) acc[m][n] = (f32x4){0.f, 0.f, 0.f, 0.f};

  for (int k0 = kbeg; k0 < kbeg + Ks; k0 += 64) {
#pragma unroll
    for (int rep = 0; rep < 4; ++rep) {        // A: 128 rows x 8 slots
      int c = rep * 256 + t;
      int row = c >> 3, ko = c & 7;
      const bf16* ga = A + (size_t)(tm * 128 + row) * K + k0 + (ko ^ (row & 7)) * 8;
      __builtin_amdgcn_global_load_lds(
          (const __attribute__((address_space(1))) unsigned int*)ga,
          (__attribute__((address_space(3))) unsigned int*)(As + row * 64 + ko * 8),
          16, 0, 0);
    }
#pragma unroll
    for (int rep = 0; rep < 2; ++rep) {        // B: 64 rows x 8 slots
      int c = rep * 256 + t;
      int row = c >> 3, ko = c & 7;
      const bf16* gb = Bt + (size_t)(tn * 64 + row) * K + k0 + (ko ^ (row & 7)) * 8;
      __builtin_amdgcn_global_load_lds(
          (const __attribute__((address_space(1))) unsigned int*)gb,
          (__attribute__((address_space(3))) unsigned int*)(Bs + row * 64 + ko * 8),
          16, 0, 0);
    }
    asm volatile("s_waitcnt vmcnt(0)" ::: "memory");
    __syncthreads();

    // k-half 0
    {
      bf16x8 af[4], bfv[2];
#pragma unroll
      for (int m = 0; m < 4; ++m) {
        int row = wr * 64 + m * 16 + rA;
        af[m] = __builtin_bit_cast(bf16x8,
            *(const u32x4*)((const char*)As + row * 128 + ((ko0 ^ (row & 7)) << 4)));
      }
#pragma unroll
      for (int n = 0; n < 2; ++n) {
        int row = wc * 32 + n * 16 + rA;
        bfv[n] = __builtin_bit_cast(bf16x8,
            *(const u32x4*)((const char*)Bs + row * 128 + ((ko0 ^ (row & 7)) << 4)));
      }
#pragma unroll
      for (int m = 0; m < 4; ++m)
#pragma unroll
        for (int n = 0; n < 2; ++n)
          acc[m][n] = __builtin_amdgcn_mfma_f32_16x16x32_bf16(af[m], bfv[n], acc[m][n], 0, 0, 0);
    }
    // k-half 1
    {
      bf16x8 af[4], bfv[2];
#pragma unroll
      for (int m = 0; m < 4; ++m) {
        int row = wr * 64 + m * 16 + rA;
        af[m] = __builtin_bit_cast(bf16x8,
            *(const u32x4*)((const char*)As + row * 128 + (((ko0 ^ (row & 7)) << 4) ^ 64)));
      }
#pragma unroll
      for (int n = 0; n < 2; ++n) {
        int row = wc * 32 + n * 16 + rA;
        bfv[n] = __builtin_bit_cast(bf16x8,
            *(const u32x4*)((const char*)Bs + row * 128 + (((ko0 ^ (row & 7)) << 4) ^ 64)));
      }
#pragma unroll
      for (int m = 0; m < 4; ++m)
#pragma unroll
        for (int n = 0; n < 2; ++n)
          acc[m][n] = __builtin_amdgcn_mfma_f32_16x16x32_bf16(af[m], bfv[n], acc[m][n], 0, 0, 0);
    }
    __syncthreads();
  }

#pragma unroll
  for (int m = 0; m < 4; ++m) {
    const int row = tm * 128 + wr * 64 + m * 16 + (lane >> 4) * 4;
#pragma unroll
    for (int n = 0; n < 2; ++n) {
      const int col = tn * 64 + wc * 32 + n * 16 + rA;
#pragma unroll
      for (int r = 0; r < 4; ++r) {
        float v = acc[m][n][r];
        if (EPI == 0) {
          ((float*)Cout)[(size_t)(row + r) * ldc + col] = v;
        } else if (EPI == 1) {
          ((float*)Cout)[(size_t)sk * M * N + (size_t)(row + r) * N + col] = v;
        } else {
          v += bias[col]; v = gelu_tanh(v);
          ((bf16*)Cout)[(size_t)(row + r) * ldc + col] = __float2bfloat16(v);
        }
      }
    }
  }
}

// ---------------- fallback GEMM (head only): 128^2, BK=32 -------------------
__global__ __launch_bounds__(256, 2)
void gemm_bt(const bf16* __restrict__ A, const bf16* __restrict__ Bt,
             void* __restrict__ Cout, const float* __restrict__ bias,
             int M, int N, int K, int ldc, int ntn)
{
  __shared__ __align__(16) bf16 As[128 * 32];
  __shared__ __align__(16) bf16 Bs[128 * 32];
  const int t = threadIdx.x;
  const int lane = t & 63;
  const int w = t >> 6;
  const int wr = w >> 1, wc = w & 1;
  const int tile = blockIdx.x;
  const int tm = tile / ntn, tn = tile % ntn;

  f32x4 acc[4][4];
#pragma unroll
  for (int m = 0; m < 4; ++m)
#pragma unroll
    for (int n = 0; n < 4; ++n) acc[m][n] = (f32x4){0.f, 0.f, 0.f, 0.f};

  const int rA = lane & 15;
  const int kq = (lane >> 4) * 8;
  const size_t a_row0 = (size_t)tm * 128;
  const int b_row0 = tn * 128;

  for (int k0 = 0; k0 < K; k0 += 32) {
#pragma unroll
    for (int i = 0; i < 2; ++i) {
      int chunk = i * 256 + t;
      int row = chunk >> 2;
      int kc = (chunk & 3) * 8;
      const bf16* ga = A + (a_row0 + row) * K + k0 + kc;
      int brow = b_row0 + row; brow = brow < N ? brow : N - 1;
      const bf16* gb = Bt + (size_t)brow * K + k0 + kc;
      __builtin_amdgcn_global_load_lds(
          (const __attribute__((address_space(1))) unsigned int*)ga,
          (__attribute__((address_space(3))) unsigned int*)(As + (size_t)(i * 256 + w * 64) * 8),
          16, 0, 0);
      __builtin_amdgcn_global_load_lds(
          (const __attribute__((address_space(1))) unsigned int*)gb,
          (__attribute__((address_space(3))) unsigned int*)(Bs + (size_t)(i * 256 + w * 64) * 8),
          16, 0, 0);
    }
    asm volatile("s_waitcnt vmcnt(0)" ::: "memory");
    __syncthreads();

    bf16x8 af[4], bfv[4];
#pragma unroll
    for (int m = 0; m < 4; ++m)
      af[m] = __builtin_bit_cast(bf16x8, *(const u32x4*)(As + (wr * 64 + m * 16 + rA) * 32 + kq));
#pragma unroll
    for (int n = 0; n < 4; ++n)
      bfv[n] = __builtin_bit_cast(bf16x8, *(const u32x4*)(Bs + (wc * 64 + n * 16 + rA) * 32 + kq));
#pragma unroll
    for (int m = 0; m < 4; ++m)
#pragma unroll
      for (int n = 0; n < 4; ++n)
        acc[m][n] = __builtin_amdgcn_mfma_f32_16x16x32_bf16(af[m], bfv[n], acc[m][n], 0, 0, 0);
    __syncthreads();
  }

#pragma unroll
  for (int m = 0; m < 4; ++m) {
    const int row = tm * 128 + wr * 64 + m * 16 + (lane >> 4) * 4;
#pragma unroll
    for (int n = 0; n < 4; ++n) {
      const int col = tn * 128 + wc * 64 + n * 16 + (lane & 15);
      if (col < N) {
#pragma unroll
        for (int r = 0; r < 4; ++r)
          ((float*)Cout)[(size_t)(row + r) * ldc + col] = acc[m][n][r];
      }
    }
  }
}

// ---------------- reduce split-K partials: + bias -> bf16 (mid MLP) ---------
__global__ __launch_bounds__(256)
void reduce_bias_bf16(const float* __restrict__ part, bf16* __restrict__ out,
                      const float* __restrict__ bias)
{
  int i = blockIdx.x * 256 + threadIdx.x;        // float4 index over ROWS*512/4
  const float4* p4 = (const float4*)part;
  const size_t str = (size_t)ROWS * DMODEL / 4;
  float4 v = p4[i];
  float4 v1 = p4[i + str], v2 = p4[i + 2 * str], v3 = p4[i + 3 * str];
  v.x += v1.x + v2.x + v3.x; v.y += v1.y + v2.y + v3.y;
  v.z += v1.z + v2.z + v3.z; v.w += v1.w + v2.w + v3.w;
  float4 bb = ((const float4*)bias)[i & (DMODEL / 4 - 1)];
  v.x += bb.x; v.y += bb.y; v.z += bb.z; v.w += bb.w;
  union { bf16 h[4]; uint2 u; } cv;
  cv.h[0] = __float2bfloat16(v.x); cv.h[1] = __float2bfloat16(v.y);
  cv.h[2] = __float2bfloat16(v.z); cv.h[3] = __float2bfloat16(v.w);
  ((uint2*)out)[i] = cv.u;
}

// -------- reduce split-K partials + residual-add into x + LayerNorm -> bf16 -
template<bool BIAS>
__global__ __launch_bounds__(256)
void reduce_resid_ln(const float* __restrict__ part, float* __restrict__ x,
                     const float* __restrict__ bias, const float* __restrict__ g,
                     const float* __restrict__ b, bf16* __restrict__ xn)
{
  int lane = threadIdx.x & 63;
  int row = blockIdx.x * 4 + (threadIdx.x >> 6);
  const float4* p4 = (const float4*)part;
  const size_t str = (size_t)ROWS * DMODEL / 4;
  size_t base = (size_t)row * (DMODEL / 4) + lane * 2;
  float4 a0 = p4[base], a1 = p4[base + 1];
#pragma unroll
  for (int s = 1; s < 4; ++s) {
    float4 q0 = p4[base + s * str], q1 = p4[base + 1 + s * str];
    a0.x += q0.x; a0.y += q0.y; a0.z += q0.z; a0.w += q0.w;
    a1.x += q1.x; a1.y += q1.y; a1.z += q1.z; a1.w += q1.w;
  }
  if (BIAS) {
    float4 b0 = ((const float4*)bias)[lane * 2];
    float4 b1 = ((const float4*)bias)[lane * 2 + 1];
    a0.x += b0.x; a0.y += b0.y; a0.z += b0.z; a0.w += b0.w;
    a1.x += b1.x; a1.y += b1.y; a1.z += b1.z; a1.w += b1.w;
  }
  float4* xr = (float4*)(x + (size_t)row * DMODEL);
  float4 x0 = xr[lane * 2], x1 = xr[lane * 2 + 1];
  x0.x += a0.x; x0.y += a0.y; x0.z += a0.z; x0.w += a0.w;
  x1.x += a1.x; x1.y += a1.y; x1.z += a1.z; x1.w += a1.w;
  xr[lane * 2] = x0; xr[lane * 2 + 1] = x1;
  float s  = x0.x + x0.y + x0.z + x0.w + x1.x + x1.y + x1.z + x1.w;
  float ss = x0.x*x0.x + x0.y*x0.y + x0.z*x0.z + x0.w*x0.w
           + x1.x*x1.x + x1.y*x1.y + x1.z*x1.z + x1.w*x1.w;
#pragma unroll
  for (int off = 32; off > 0; off >>= 1) { s += __shfl_xor(s, off); ss += __shfl_xor(ss, off); }
  float mu = s * (1.f / DMODEL);
  float inv = rsqrtf(ss * (1.f / DMODEL) - mu * mu + 1e-5f);
  int c0 = lane * 8;
  float vv[8] = {x0.x, x0.y, x0.z, x0.w, x1.x, x1.y, x1.z, x1.w};
#pragma unroll
  for (int j = 0; j < 8; ++j)
    xn[(size_t)row * DMODEL + c0 + j] = __float2bfloat16((vv[j] - mu) * inv * g[c0 + j] + b[c0 + j]);
}

// ---------------- Embedding + first LayerNorm -------------------------------
__global__ __launch_bounds__(256)
void embed_ln(const int* __restrict__ ids, const float* __restrict__ te,
              const float* __restrict__ pe, const float* __restrict__ g,
              const float* __restrict__ b, float* __restrict__ x, bf16* __restrict__ xn)
{
  int lane = threadIdx.x & 63;
  int row = blockIdx.x * 4 + (threadIdx.x >> 6);
  int sq = row & (SEQ - 1);
  int id = ids[row];
  const float4* tr = (const float4*)(te + (size_t)id * DMODEL);
  const float4* pr = (const float4*)(pe + (size_t)sq * DMODEL);
  float4 x0 = tr[lane * 2], x1 = tr[lane * 2 + 1];
  float4 p0 = pr[lane * 2], p1 = pr[lane * 2 + 1];
  x0.x += p0.x; x0.y += p0.y; x0.z += p0.z; x0.w += p0.w;
  x1.x += p1.x; x1.y += p1.y; x1.z += p1.z; x1.w += p1.w;
  float4* xr = (float4*)(x + (size_t)row * DMODEL);
  xr[lane * 2] = x0; xr[lane * 2 + 1] = x1;
  float s  = x0.x + x0.y + x0.z + x0.w + x1.x + x1.y + x1.z + x1.w;
  float ss = x0.x*x0.x + x0.y*x0.y + x0.z*x0.z + x0.w*x0.w
           + x1.x*x1.x + x1.y*x1.y + x1.z*x1.z + x1.w*x1.w;
#pragma unroll
  for (int off = 32; off > 0; off >>= 1) { s += __shfl_xor(s, off); ss += __shfl_xor(ss, off); }
  float mu = s * (1.f / DMODEL);
  float inv = rsqrtf(ss * (1.f / DMODEL) - mu * mu + 1e-5f);
  int c0 = lane * 8;
  float vv[8] = {x0.x, x0.y, x0.z, x0.w, x1.x, x1.y, x1.z, x1.w};
#pragma unroll
  for (int j = 0; j < 8; ++j)
    xn[(size_t)row * DMODEL + c0 + j] = __float2bfloat16((vv[j] - mu) * inv * g[c0 + j] + b[c0 + j]);
}

// ---------------- fp32 [R][C] -> bf16 [C][R] transpose+convert (batched) ----
__global__ __launch_bounds__(256)
void transpose_cvt(const float* __restrict__ in, bf16* __restrict__ out, int R, int C)
{
  __shared__ float tile[32][33];
  int mat = blockIdx.z;
  const float* src = in + (size_t)mat * R * C;
  bf16* dst = out + (size_t)mat * R * C;
  int c0 = blockIdx.x * 32, r0 = blockIdx.y * 32;
  int tx = threadIdx.x, ty = threadIdx.y;
#pragma unroll
  for (int i = ty; i < 32; i += 8)
    tile[i][tx] = src[(size_t)(r0 + i) * C + c0 + tx];
  __syncthreads();
#pragma unroll
  for (int i = ty; i < 32; i += 8)
    dst[(size_t)(c0 + i) * R + r0 + tx] = __float2bfloat16(tile[tx][i]);
}

// ---------------- Q/K/V weights -> fused transposed bf16 [l][1536][512] -----
__global__ __launch_bounds__(256)
void transpose_qkv(const float* __restrict__ Wq, const float* __restrict__ Wk,
                   const float* __restrict__ Wv, bf16* __restrict__ out)
{
  __shared__ float tile[32][33];
  int z = blockIdx.z;                 // l*3 + p
  int l = z / 3, p = z % 3;
  const float* src = (p == 0 ? Wq : (p == 1 ? Wk : Wv)) + (size_t)l * DMODEL * DMODEL;
  bf16* dst = out + (size_t)l * QKVW * DMODEL + (size_t)p * DMODEL * DMODEL;
  int c0 = blockIdx.x * 32, r0 = blockIdx.y * 32;
  int tx = threadIdx.x, ty = threadIdx.y;
#pragma unroll
  for (int i = ty; i < 32; i += 8)
    tile[i][tx] = src[(size_t)(r0 + i) * DMODEL + c0 + tx];
  __syncthreads();
#pragma unroll
  for (int i = ty; i < 32; i += 8)
    dst[(size_t)(c0 + i) * DMODEL + r0 + tx] = __float2bfloat16(tile[tx][i]);
}

// ---------------- fp32 -> bf16 convert (tok_emb for tied head) --------------
__global__ void cvt_bf16_k(const float* __restrict__ in, bf16* __restrict__ out, int n4)
{
  int i = blockIdx.x * 256 + threadIdx.x;
  if (i >= n4) return;
  float4 v = ((const float4*)in)[i];
  union { bf16 h[4]; uint2 u; } cv;
  cv.h[0] = __float2bfloat16(v.x); cv.h[1] = __float2bfloat16(v.y);
  cv.h[2] = __float2bfloat16(v.z); cv.h[3] = __float2bfloat16(v.w);
  ((uint2*)out)[i] = cv.u;
}

// ---------------- attention: per-chunk K^T V partial sums -------------------
__global__ __launch_bounds__(256)
void scan_ktv(const float* __restrict__ qkv, float* __restrict__ ktv)
{
  int blk = blockIdx.x;             // bh*NCHUNK + c
  int c = blk & (NCHUNK - 1), bh = blk >> 5;
  int b = bh >> 3, h = bh & 7;
  __shared__ float ks[CHUNK][64], vs[CHUNK][64];
  int t = threadIdx.x;
  size_t base = ((size_t)(b * SEQ + c * CHUNK)) * QKVW + h * HD;
#pragma unroll
  for (int i = 0; i < CHUNK * 64 / 256; ++i) {
    int idx = i * 256 + t;
    int s = idx >> 6, e = idx & 63;
    ks[s][e] = qkv[base + 512 + (size_t)s * QKVW + e];
    vs[s][e] = qkv[base + 1024 + (size_t)s * QKVW + e];
  }
  __syncthreads();
  int e = t >> 2, d0 = (t & 3) * 16;
  float acc[16];
#pragma unroll
  for (int j = 0; j < 16; ++j) acc[j] = 0.f;
  for (int s = 0; s < CHUNK; ++s) {
    float kv = ks[s][e];
#pragma unroll
    for (int j = 0; j < 16; ++j) acc[j] += kv * vs[s][d0 + j];
  }
  float* o = ktv + (size_t)blk * 4096 + e * 64 + d0;
#pragma unroll
  for (int j = 0; j < 16; ++j) o[j] = acc[j];
}

// ---------------- attention: y = (QK^T . causal) V + Q M_prefix -------------
__global__ __launch_bounds__(256)
void scan_attn(const float* __restrict__ qkv, const float* __restrict__ ktv,
               bf16* __restrict__ y)
{
  int blk = blockIdx.x;
  int c = blk & (NCHUNK - 1), bh = blk >> 5;
  int b = bh >> 3, h = bh & 7;
  __shared__ float qs[CHUNK][65], ks[CHUNK][65], vs[CHUNK][65];
  __shared__ float Ss[CHUNK][CHUNK + 1];
  __shared__ float Ms[64][65];
  int t = threadIdx.x;
  size_t base = ((size_t)(b * SEQ + c * CHUNK)) * QKVW + h * HD;
#pragma unroll
  for (int i = 0; i < CHUNK * 64 / 256; ++i) {
    int idx = i * 256 + t;
    int s = idx >> 6, e = idx & 63;
    qs[s][e] = qkv[base + (size_t)s * QKVW + e];
    ks[s][e] = qkv[base + 512 + (size_t)s * QKVW + e];
    vs[s][e] = qkv[base + 1024 + (size_t)s * QKVW + e];
  }
  {  // prefix-sum of K^T V chunks before this one
    int e = t >> 2, d0 = (t & 3) * 16;
    float mp[16];
#pragma unroll
    for (int j = 0; j < 16; ++j) mp[j] = 0.f;
    for (int cp = 0; cp < c; ++cp) {
      const float* p = ktv + ((size_t)bh * NCHUNK + cp) * 4096 + e * 64 + d0;
#pragma unroll
      for (int j = 0; j < 16; ++j) mp[j] += p[j];
    }
#pragma unroll
    for (int j = 0; j < 16; ++j) Ms[e][d0 + j] = mp[j];
  }
  __syncthreads();
  {  // S = Q K^T with inclusive causal mask
    int si = t >> 3, j0 = (t & 7) * 4;
    float sa[4] = {0.f, 0.f, 0.f, 0.f};
    for (int e = 0; e < 64; ++e) {
      float qv = qs[si][e];
#pragma unroll
      for (int j = 0; j < 4; ++j) sa[j] += qv * ks[j0 + j][e];
    }
#pragma unroll
    for (int j = 0; j < 4; ++j) Ss[si][j0 + j] = (j0 + j <= si) ? sa[j] : 0.f;
  }
  __syncthreads();
  {  // y = S V + Q M
    int si = t >> 3, d0 = (t & 7) * 8;
    float ya[8];
#pragma unroll
    for (int j = 0; j < 8; ++j) ya[j] = 0.f;
    for (int sp = 0; sp < CHUNK; ++sp) {
      float sv = Ss[si][sp];
#pragma unroll
      for (int j = 0; j < 8; ++j) ya[j] += sv * vs[sp][d0 + j];
    }
    for (int e = 0; e < 64; ++e) {
      float qv = qs[si][e];
#pragma unroll
      for (int j = 0; j < 8; ++j) ya[j] += qv * Ms[e][d0 + j];
    }
    bf16* o = y + ((size_t)(b * SEQ + c * CHUNK + si)) * DMODEL + h * HD + d0;
#pragma unroll
    for (int j = 0; j < 8; ++j) o[j] = __float2bfloat16(ya[j]);
  }
}

// ---------------------------------------------------------------------------
extern "C" void kernel_launch(void* const* d_in, const int* in_sizes, int n_in,
                              void* d_out, int out_size, void* d_ws, size_t ws_size,
                              hipStream_t stream)
{
  const int*   ids  = (const int*)  d_in[0];
  const float* tok  = (const float*)d_in[1];
  const float* pos  = (const float*)d_in[2];
  const float* Wq   = (const float*)d_in[3];
  const float* Wk   = (const float*)d_in[4];
  const float* Wv   = (const float*)d_in[5];
  const float* Wo   = (const float*)d_in[6];
  const float* ln1g = (const float*)d_in[7];
  const float* ln1b = (const float*)d_in[8];
  const float* ln2g = (const float*)d_in[9];
  const float* ln2b = (const float*)d_in[10];
  const float* lnfg = (const float*)d_in[11];
  const float* lnfb = (const float*)d_in[12];
  const float* W1   = (const float*)d_in[13];
  const float* b1   = (const float*)d_in[14];
  const float* W2   = (const float*)d_in[15];
  const float* b2   = (const float*)d_in[16];
  float* out = (float*)d_out;

  char* ws = (char*)d_ws;
  size_t off = 0;
  auto alloc = [&](size_t bytes) { void* p = ws + off; off += (bytes + 255) & ~(size_t)255; return p; };
  bf16* QKVt = (bf16*)alloc((size_t)2 * QKVW * 512 * 2);
  bf16* Wot  = (bf16*)alloc((size_t)2 * 512 * 512 * 2);
  bf16* W1t  = (bf16*)alloc((size_t)6 * 512 * 2048 * 2);
  bf16* W2t  = (bf16*)alloc((size_t)6 * 2048 * 512 * 2);
  bf16* tokb = (bf16*)alloc((size_t)VOCABN * 512 * 2);
  float* x   = (float*)alloc((size_t)ROWS * 512 * 4);
  bf16*  xn  = (bf16*) alloc((size_t)ROWS * 512 * 2);
  bf16*  tbuf= (bf16*) alloc((size_t)ROWS * 512 * 2);
  bf16*  hbuf= (bf16*) alloc((size_t)ROWS * 2048 * 2);
  float* qkvf= (float*)alloc((size_t)ROWS * QKVW * 4);
  bf16*  yb  = (bf16*) alloc((size_t)ROWS * 512 * 2);
  float* ktv = (float*)alloc((size_t)16 * NCHUNK * 4096 * 4);
  float* part= (float*)alloc((size_t)4 * ROWS * 512 * 4);

  dim3 tb(32, 8);
  transpose_qkv<<<dim3(16, 16, 6), tb, 0, stream>>>(Wq, Wk, Wv, QKVt);
  transpose_cvt<<<dim3(16, 16, 2), tb, 0, stream>>>(Wo, Wot, 512, 512);
  transpose_cvt<<<dim3(64, 16, 6), tb, 0, stream>>>(W1, W1t, 512, 2048);
  transpose_cvt<<<dim3(16, 64, 6), tb, 0, stream>>>(W2, W2t, 2048, 512);
  int n4 = VOCABN * 512 / 4;
  cvt_bf16_k<<<(n4 + 255) / 256, 256, 0, stream>>>(tok, tokb, n4);

  embed_ln<<<ROWS / 4, 256, 0, stream>>>(ids, tok, pos, ln1g, ln1b, x, xn);

  for (int l = 0; l < 2; ++l) {
    // fused QKV projection: [2048,1536] fp32 — 384 blocks
    gemm_mid<0><<<dim3(16 * (QKVW / 64)), 256, 0, stream>>>(
        xn, QKVt + (size_t)l * QKVW * 512, qkvf, nullptr, ROWS, QKVW, 512, 512, QKVW, QKVW / 64);
    scan_ktv<<<16 * NCHUNK, 256, 0, stream>>>(qkvf, ktv);
    scan_attn<<<16 * NCHUNK, 256, 0, stream>>>(qkvf, ktv, yb);
    // Wo split-K=4 (512 blocks), reduce + residual + ln2
    gemm_mid<1><<<dim3(16 * 8, 4), 256, 0, stream>>>(
        yb, Wot + (size_t)l * 512 * 512, part, nullptr, ROWS, 512, 512, 128, 512, 8);
    reduce_resid_ln<false><<<ROWS / 4, 256, 0, stream>>>(
        part, x, nullptr, ln2g + l * 512, ln2b + l * 512, xn);

    const bf16* cur = xn;
    for (int m = 0; m < 3; ++m) {
      int lm = l * 3 + m;
      // W1: [2048,2048] gelu -> bf16 — 512 blocks
      gemm_mid<2><<<dim3(16 * (2048 / 64)), 256, 0, stream>>>(
          cur, W1t + (size_t)lm * 2048 * 512, hbuf, b1 + (size_t)lm * 2048,
          ROWS, 2048, 512, 512, 2048, 2048 / 64);
      // W2: split-K=4 (512 blocks)
      gemm_mid<1><<<dim3(16 * 8, 4), 256, 0, stream>>>(
          hbuf, W2t + (size_t)lm * 512 * 2048, part, nullptr, ROWS, 512, 2048, 512, 512, 8);
      if (m < 2) {
        reduce_bias_bf16<<<ROWS * 512 / 4 / 256, 256, 0, stream>>>(part, tbuf, b2 + (size_t)lm * 512);
        cur = tbuf;
      } else {
        const float* g = (l == 0) ? (ln1g + 512) : lnfg;
        const float* b = (l == 0) ? (ln1b + 512) : lnfb;
        reduce_resid_ln<true><<<ROWS / 4, 256, 0, stream>>>(part, x, b2 + (size_t)lm * 512, g, b, xn);
      }
    }
  }

  // tied head: R9-exact 8-phase 256^2, BK=64, 128 KiB dynamic LDS, tn-major
  int ntn_h = (VOCABN + 255) / 256;   // 197
  (void)hipFuncSetAttribute((const void*)head_gemm8,
                            hipFuncAttributeMaxDynamicSharedMemorySize, 131072);
  head_gemm8<<<dim3(8 * ntn_h), 512, 131072, stream>>>(xn, tokb, out, VOCABN, ntn_h);
  if (hipGetLastError() != hipSuccess) {
    // fallback: 128^2 m97-structure head
    gemm_bt<<<dim3((ROWS / 128) * ((VOCABN + 127) / 128)), 256, 0, stream>>>(
        xn, tokb, out, nullptr, ROWS, VOCABN, 512, VOCABN, (VOCABN + 127) / 128);
  }
}